// Round 1
// baseline (254.053 us; speedup 1.0000x reference)
//
#include <hip/hip_runtime.h>
#include <hip/hip_bf16.h>

typedef __attribute__((ext_vector_type(8))) short short8;
typedef __attribute__((ext_vector_type(4))) short short4v;
typedef __attribute__((ext_vector_type(4))) float f32x4;

#define B_ 16
#define T_ 1024
#define C_ 512
#define NH 8
#define HD 64

__device__ __forceinline__ short f2bf(float f) {
  union { float f; unsigned u; } v;
  v.f = f;
  unsigned r = v.u + 0x7fffu + ((v.u >> 16) & 1u);
  return (short)(r >> 16);
}

__device__ __forceinline__ short2 pack_bf2(float a, float b) {
  __hip_bfloat162 t = __float22bfloat162_rn(make_float2(a, b));
  short2 r;
  __builtin_memcpy(&r, &t, 4);
  return r;
}

// bare v_exp_f32: computes 2^x. The softmax scale folds log2(e) into Q
// at gemm_qkv, so scores arrive pre-multiplied — saves one v_mul per exp.
__device__ __forceinline__ float fexp2(float x) {
  float r;
  asm("v_exp_f32 %0, %1" : "=v"(r) : "v"(x));
  return r;
}

__device__ __forceinline__ void gload_lds16(const short* g, short* l) {
  __builtin_amdgcn_global_load_lds(
      (const __attribute__((address_space(1))) void*)g,
      (__attribute__((address_space(3))) void*)l, 16, 0, 0);
}

// ---------------- stage 1a: partial sums ----------------
__global__ __launch_bounds__(256) void stats1_kernel(const float* __restrict__ x,
                                                     float2* __restrict__ partials) {
  int chunk = blockIdx.x;
  int b = blockIdx.y;
  int tid = threadIdx.x;
  const float4* xb = (const float4*)(x + (size_t)b * 524288 + (size_t)chunk * 8192);
  float s = 0.f, s2 = 0.f;
#pragma unroll
  for (int i = 0; i < 8; i++) {
    float4 v = xb[tid + i * 256];
    s  += v.x + v.y + v.z + v.w;
    s2 += v.x * v.x + v.y * v.y + v.z * v.z + v.w * v.w;
  }
  __shared__ float ls[256], ls2[256];
  ls[tid] = s; ls2[tid] = s2;
  __syncthreads();
  for (int o = 128; o > 0; o >>= 1) {
    if (tid < o) { ls[tid] += ls[tid + o]; ls2[tid] += ls2[tid + o]; }
    __syncthreads();
  }
  if (tid == 0) partials[b * 64 + chunk] = make_float2(ls[0], ls2[0]);
}

// ---------------- stage 1b: final reduce ----------------
__global__ __launch_bounds__(64) void stats2_kernel(const float2* __restrict__ partials,
                                                    float* __restrict__ stats) {
  int b = blockIdx.x;
  float2 p = partials[b * 64 + threadIdx.x];
  float s = p.x, s2 = p.y;
#pragma unroll
  for (int off = 1; off < 64; off <<= 1) {
    s  += __shfl_xor(s,  off, 64);
    s2 += __shfl_xor(s2, off, 64);
  }
  if (threadIdx.x == 0) {
    float mean = s * (1.f / 524288.f);
    float var  = s2 * (1.f / 524288.f) - mean * mean;
    stats[b * 2]     = mean;
    stats[b * 2 + 1] = rsqrtf(var + 1e-5f);
  }
}

// ---------------- stage 2: normalize + affine -> bf16 ----------------
__global__ __launch_bounds__(256) void norm_kernel(const float* __restrict__ x,
                                                   const float* __restrict__ gamma,
                                                   const float* __restrict__ beta,
                                                   const float* __restrict__ stats,
                                                   short* __restrict__ xn) {
  size_t i4 = (size_t)blockIdx.x * 256 + threadIdx.x;
  float4 v = ((const float4*)x)[i4];
  size_t i = i4 * 4;
  int b = (int)(i >> 19);
  int c = (int)(i & 511);
  float mean = stats[b * 2], rstd = stats[b * 2 + 1];
  short4v o;
  o[0] = f2bf((v.x - mean) * rstd * gamma[c + 0] + beta[c + 0]);
  o[1] = f2bf((v.y - mean) * rstd * gamma[c + 1] + beta[c + 1]);
  o[2] = f2bf((v.z - mean) * rstd * gamma[c + 2] + beta[c + 2]);
  o[3] = f2bf((v.w - mean) * rstd * gamma[c + 3] + beta[c + 3]);
  ((short4v*)xn)[i4] = o;
}

// ---------------- stage 3: weights fp32 (K,N) -> bf16 transposed ----------------
__global__ __launch_bounds__(256) void transpose_w_all(const float* __restrict__ wq,
                                                       const float* __restrict__ wk,
                                                       const float* __restrict__ wv,
                                                       const float* __restrict__ wo,
                                                       short* __restrict__ wqkvT,
                                                       short* __restrict__ woT) {
  int o = blockIdx.x * 256 + threadIdx.x;
  int sel = o >> 18;
  int oo = o & 262143;
  int k = oo >> 9, n = oo & 511;
  const float* w = (sel == 0) ? wq : (sel == 1) ? wk : (sel == 2) ? wv : wo;
  float val = w[oo];
  if (sel < 3) wqkvT[((size_t)(sel * 512 + n)) * 512 + k] = f2bf(val);
  else         woT[(size_t)n * 512 + k] = f2bf(val);
}

// ---------------- stage 4: fused QKV GEMM (m97 structure) ----------------
// Q segment (seg 0) pre-scaled by 0.125*log2(e): folds both the softmax
// 1/sqrt(64) scale AND the exp->exp2 base conversion (softmax is
// base-invariant when applied consistently; attn uses raw v_exp_f32).
__global__ __launch_bounds__(256) void gemm_qkv(const short* __restrict__ A,
                                                const short* __restrict__ Bt,
                                                const float* __restrict__ bq,
                                                const float* __restrict__ bk,
                                                const float* __restrict__ bv,
                                                short* __restrict__ C) {
  __shared__ __align__(16) short As[128 * 32];
  __shared__ __align__(16) short Bs[128 * 32];
  int tid = threadIdx.x;
  int w = tid >> 6, lane = tid & 63;
  int quad = lane >> 4, l16 = lane & 15;
  int mw = (w >> 1) * 64, nw = (w & 1) * 64;
  int seg = (blockIdx.x * 128) >> 9;
  const float* bias = (seg == 0) ? bq : (seg == 1) ? bk : bv;
  float smul = (seg == 0) ? 0.18033688011112042f : 1.0f;
  const short* Atile = A + (size_t)(blockIdx.y * 128) * 512;
  const short* Btile = Bt + (size_t)(blockIdx.x * 128) * 512;
  int srow = (w << 4) + (lane >> 2);
  int scol = (lane & 3) * 8;
  f32x4 acc[4][4] = {};
  for (int k0 = 0; k0 < 512; k0 += 32) {
    __syncthreads();
    gload_lds16(&Atile[(size_t)srow * 512 + k0 + scol],        &As[w * 512]);
    gload_lds16(&Atile[(size_t)(srow + 64) * 512 + k0 + scol], &As[2048 + w * 512]);
    gload_lds16(&Btile[(size_t)srow * 512 + k0 + scol],        &Bs[w * 512]);
    gload_lds16(&Btile[(size_t)(srow + 64) * 512 + k0 + scol], &Bs[2048 + w * 512]);
    __syncthreads();
    short8 af[4], bf[4];
#pragma unroll
    for (int i = 0; i < 4; i++) af[i] = *(const short8*)(&As[(mw + i * 16 + l16) * 32 + quad * 8]);
#pragma unroll
    for (int i = 0; i < 4; i++) bf[i] = *(const short8*)(&Bs[(nw + i * 16 + l16) * 32 + quad * 8]);
#pragma unroll
    for (int mi = 0; mi < 4; mi++)
#pragma unroll
      for (int ni = 0; ni < 4; ni++)
        acc[mi][ni] = __builtin_amdgcn_mfma_f32_16x16x32_bf16(af[mi], bf[ni], acc[mi][ni], 0, 0, 0);
  }
  int m0 = blockIdx.y * 128 + mw;
  int n0 = blockIdx.x * 128 + nw;
#pragma unroll
  for (int mi = 0; mi < 4; mi++)
#pragma unroll
    for (int ni = 0; ni < 4; ni++) {
      int col = n0 + ni * 16 + l16;
      float bval = bias[col & 511];
#pragma unroll
      for (int r = 0; r < 4; r++) {
        int row = m0 + mi * 16 + quad * 4 + r;
        C[(size_t)row * 1536 + col] = f2bf((acc[mi][ni][r] + bval) * smul);
      }
    }
}

// ---------------- stage 6: GEMM + bias + residual (fp32 out) ----------------
__global__ __launch_bounds__(256) void gemm_out(const short* __restrict__ A,
                                                const short* __restrict__ Bt,
                                                const float* __restrict__ bias,
                                                const float* __restrict__ xres,
                                                float* __restrict__ out) {
  __shared__ __align__(16) short As[128 * 32];
  __shared__ __align__(16) short Bs[128 * 32];
  int tid = threadIdx.x;
  int w = tid >> 6, lane = tid & 63;
  int quad = lane >> 4, l16 = lane & 15;
  int mw = (w >> 1) * 64, nw = (w & 1) * 64;
  const short* Atile = A + (size_t)(blockIdx.y * 128) * 512;
  const short* Btile = Bt + (size_t)(blockIdx.x * 128) * 512;
  int srow = (w << 4) + (lane >> 2);
  int scol = (lane & 3) * 8;
  f32x4 acc[4][4] = {};
  for (int k0 = 0; k0 < 512; k0 += 32) {
    __syncthreads();
    gload_lds16(&Atile[(size_t)srow * 512 + k0 + scol],        &As[w * 512]);
    gload_lds16(&Atile[(size_t)(srow + 64) * 512 + k0 + scol], &As[2048 + w * 512]);
    gload_lds16(&Btile[(size_t)srow * 512 + k0 + scol],        &Bs[w * 512]);
    gload_lds16(&Btile[(size_t)(srow + 64) * 512 + k0 + scol], &Bs[2048 + w * 512]);
    __syncthreads();
    short8 af[4], bf[4];
#pragma unroll
    for (int i = 0; i < 4; i++) af[i] = *(const short8*)(&As[(mw + i * 16 + l16) * 32 + quad * 8]);
#pragma unroll
    for (int i = 0; i < 4; i++) bf[i] = *(const short8*)(&Bs[(nw + i * 16 + l16) * 32 + quad * 8]);
#pragma unroll
    for (int mi = 0; mi < 4; mi++)
#pragma unroll
      for (int ni = 0; ni < 4; ni++)
        acc[mi][ni] = __builtin_amdgcn_mfma_f32_16x16x32_bf16(af[mi], bf[ni], acc[mi][ni], 0, 0, 0);
  }
  int m0 = blockIdx.y * 128 + mw;
  int n0 = blockIdx.x * 128 + nw;
#pragma unroll
  for (int mi = 0; mi < 4; mi++)
#pragma unroll
    for (int ni = 0; ni < 4; ni++) {
      int col = n0 + ni * 16 + l16;
      float bval = bias[col];
#pragma unroll
      for (int r = 0; r < 4; r++) {
        int row = m0 + mi * 16 + quad * 4 + r;
        out[(size_t)row * 512 + col] = acc[mi][ni][r] + bval + xres[(size_t)row * 512 + col];
      }
    }
}

// ---------------- stage 4b: V -> vT[b][h][d][slot-permuted keys] ----------------
// Slot layout per 128-key chunk: slot = w*32 + q*8 + half*4 + r for key
// kt = half*64 + w*16 + q*4 + r, so attn's PV A-frag (wave w, quad q) is one
// contiguous 16B read.
__global__ __launch_bounds__(256) void vtrans_kernel(const short* __restrict__ qkv,
                                                     short* __restrict__ vT) {
  int chunk = blockIdx.x;  // 0..7 (128-token chunks)
  int h  = blockIdx.y;
  int b  = blockIdx.z;
  int tid = threadIdx.x;
  __shared__ short TB[128 * 72];
  const short* src = qkv + ((size_t)b * T_ + chunk * 128) * 1536 + 1024 + (size_t)h * 64;
#pragma unroll
  for (int i = 0; i < 4; i++) {
    int idx = tid + i * 256;
    int t = idx >> 3, c = idx & 7;
    *(short8*)(&TB[t * 72 + c * 8]) = *(const short8*)(src + (size_t)t * 1536 + c * 8);
  }
  __syncthreads();
  short* dst = vT + ((size_t)(b * 8 + h) * 64) * 1024 + chunk * 128;
#pragma unroll
  for (int i = 0; i < 4; i++) {
    int idx = tid + i * 256;
    int d = idx >> 4, sc = idx & 15;
    int w2 = sc >> 2, q2 = sc & 3;
    short8 o;
#pragma unroll
    for (int sg = 0; sg < 8; sg++) {
      int half = sg >> 2, r = sg & 3;
      o[sg] = TB[(half * 64 + w2 * 16 + q2 * 4 + r) * 72 + d];
    }
    *(short8*)(dst + (size_t)d * 1024 + sc * 8) = o;
  }
}

// ---------------- stage 5: attention — barrier-free, register-direct ----------------
// No LDS staging in the main loop: each wave consumes ONLY its own 32 keys
// per 128-key tile, so the previous global->LDS->reg round trip had zero
// cross-wave sharing and cost two full-block barriers (vmcnt(0) drain) per
// tile. Fragments are loaded straight global->VGPR (16B/lane, naturally
// aligned); K+V per (b,h) is 256 KB and all 16 qt-blocks of one bh land on
// the same XCD (qt strides linear block id by 128 === 0 mod 8) -> L2-hit.
// K is software-pipelined 2-deep in registers; V is issued at iteration top
// (before the K prefetch, so its wait is vmcnt(4), not a drain) and consumed
// after the exp chain. Waves free-run; MFMA/VALU overlap across waves.
// Scores arrive pre-scaled by 0.125*log2(e) -> bare v_exp_f32 == softmax exp.
__global__ __launch_bounds__(256) void attn_kernel(const short* __restrict__ Q,
                                                   const short* __restrict__ Kmat,
                                                   const short* __restrict__ vTg,
                                                   short* __restrict__ O) {
  int tid = threadIdx.x;
  int w = tid >> 6, lane = tid & 63;
  int quad = lane >> 4, l16 = lane & 15;
  int bh = blockIdx.x;   // b*8+h
  int qt = blockIdx.y;
  int b = bh >> 3, h = bh & 7;
  size_t base  = ((size_t)b * T_) * 1536 + (size_t)h * 64;
  size_t vbase = ((size_t)bh * 64) * 1024;
  size_t obase = ((size_t)b * T_) * 512 + (size_t)h * 64;
  int qrow0 = qt * 64;

  __shared__ __align__(16) char smem[17408 + 1024];   // epilogue only
  float* Lbuf = (float*)smem;                         // [q][d] pad 68
  float* denomL = (float*)(smem + 17408);

  // Q as B-frags: B[k=d=quad*8+j][n=q=l16], 4 q-tiles x 2 d-halves
  short8 qf0[4], qf1[4];
#pragma unroll
  for (int g = 0; g < 4; g++) {
    const short* qp = Q + base + (size_t)(qrow0 + g * 16 + l16) * 1536 + quad * 8;
    qf0[g] = *(const short8*)qp;
    qf1[g] = *(const short8*)(qp + 32);
  }

  // K fragment base: key = w*16 + l16 (+64 for kp1), d = quad*8 (+32 imm)
  const short* kp0 = Kmat + base + (size_t)(w * 16 + l16) * 1536 + quad * 8;
  const short* kp1 = kp0 + 64 * 1536;
  // V fragment base: d-row = l16 (+f*16 rows), key-slot = w*4+quad
  const short* vp0 = vTg + vbase + (size_t)l16 * 1024 + (w * 4 + quad) * 8;

  f32x4 oacc[4][4] = {};   // O^T[d-tile f][q-tile g]
  float lsum[4] = {0.f, 0.f, 0.f, 0.f};

  // prologue: tile 0 K fragments
  short8 ka0 = *(const short8*)kp0;
  short8 ka1 = *(const short8*)(kp0 + 32);
  short8 ka2 = *(const short8*)kp1;
  short8 ka3 = *(const short8*)(kp1 + 32);

#pragma unroll
  for (int t = 0; t < 8; t++) {
    // V for tile t: issued first so the pre-PV wait leaves K(t+1) in flight
    short8 vfr[4];
#pragma unroll
    for (int f = 0; f < 4; f++)
      vfr[f] = *(const short8*)(vp0 + (size_t)f * 16384 + t * 128);
    // K prefetch for tile t+1
    short8 kn0, kn1, kn2, kn3;
    if (t < 7) {
      const short* p0 = kp0 + (size_t)(t + 1) * 196608;
      const short* p1 = kp1 + (size_t)(t + 1) * 196608;
      kn0 = *(const short8*)p0;
      kn1 = *(const short8*)(p0 + 32);
      kn2 = *(const short8*)p1;
      kn3 = *(const short8*)(p1 + 32);
    }
#pragma unroll
    for (int g = 0; g < 4; g++) {
      f32x4 za = {}, zb = {};
      za = __builtin_amdgcn_mfma_f32_16x16x32_bf16(ka0, qf0[g], za, 0, 0, 0);
      za = __builtin_amdgcn_mfma_f32_16x16x32_bf16(ka1, qf1[g], za, 0, 0, 0);
      zb = __builtin_amdgcn_mfma_f32_16x16x32_bf16(ka2, qf0[g], zb, 0, 0, 0);
      zb = __builtin_amdgcn_mfma_f32_16x16x32_bf16(ka3, qf1[g], zb, 0, 0, 0);
      float pa0 = fexp2(za[0]), pa1 = fexp2(za[1]);
      float pa2 = fexp2(za[2]), pa3 = fexp2(za[3]);
      float pb0 = fexp2(zb[0]), pb1 = fexp2(zb[1]);
      float pb2 = fexp2(zb[2]), pb3 = fexp2(zb[3]);
      lsum[g] += (pa0 + pa1) + (pa2 + pa3) + ((pb0 + pb1) + (pb2 + pb3));
      short2 a01 = pack_bf2(pa0, pa1), a23 = pack_bf2(pa2, pa3);
      short2 b01 = pack_bf2(pb0, pb1), b23 = pack_bf2(pb2, pb3);
      short8 pf;
      pf[0] = a01.x; pf[1] = a01.y; pf[2] = a23.x; pf[3] = a23.y;
      pf[4] = b01.x; pf[5] = b01.y; pf[6] = b23.x; pf[7] = b23.y;
#pragma unroll
      for (int f = 0; f < 4; f++)
        oacc[f][g] = __builtin_amdgcn_mfma_f32_16x16x32_bf16(vfr[f], pf, oacc[f][g], 0, 0, 0);
    }
    if (t < 7) { ka0 = kn0; ka1 = kn1; ka2 = kn2; ka3 = kn3; }
  }

  // per-lane lsum covers this wave's keys for query g*16+l16; sum over quads
#pragma unroll
  for (int g = 0; g < 4; g++) {
    lsum[g] += __shfl_xor(lsum[g], 16, 64);
    lsum[g] += __shfl_xor(lsum[g], 32, 64);
  }
  if (quad == 0) {
#pragma unroll
    for (int g = 0; g < 4; g++) denomL[w * 64 + g * 16 + l16] = lsum[g];
  }
  // sequential cross-wave accumulation of O^T into Lbuf (transposed to [q][d])
  for (int ww = 0; ww < 4; ww++) {
    __syncthreads();
    if (w == ww) {
#pragma unroll
      for (int g = 0; g < 4; g++)
#pragma unroll
        for (int f = 0; f < 4; f++) {
          float* p = &Lbuf[(g * 16 + l16) * 68 + f * 16 + quad * 4];
          if (ww == 0) *(f32x4*)p = oacc[f][g];
          else         *(f32x4*)p = *(f32x4*)p + oacc[f][g];
        }
    }
  }
  __syncthreads();

  // coalesced writeout: thread -> (q = tid/4, 16-wide d segment)
  int q = tid >> 2, seg = tid & 3;
  float dn = denomL[q] + denomL[64 + q] + denomL[128 + q] + denomL[192 + q];
  float rinv = __frcp_rn(dn);
  const float* row = &Lbuf[q * 68 + seg * 16];
  short8 o0, o1;
#pragma unroll
  for (int i = 0; i < 8; i++) o0[i] = f2bf(row[i] * rinv);
#pragma unroll
  for (int i = 0; i < 8; i++) o1[i] = f2bf(row[8 + i] * rinv);
  short* op = O + obase + (size_t)(qrow0 + q) * 512 + seg * 16;
  *(short8*)op = o0;
  *(short8*)(op + 8) = o1;
}

extern "C" void kernel_launch(void* const* d_in, const int* in_sizes, int n_in,
                              void* d_out, int out_size, void* d_ws, size_t ws_size,
                              hipStream_t stream) {
  const float* x     = (const float*)d_in[0];
  const float* gamma = (const float*)d_in[1];
  const float* beta  = (const float*)d_in[2];
  const float* wq    = (const float*)d_in[3];
  const float* bq    = (const float*)d_in[4];
  const float* wk    = (const float*)d_in[5];
  const float* bk    = (const float*)d_in[6];
  const float* wv    = (const float*)d_in[7];
  const float* bv    = (const float*)d_in[8];
  const float* wo    = (const float*)d_in[9];
  const float* bo    = (const float*)d_in[10];
  float* out = (float*)d_out;

  char* ws = (char*)d_ws;
  const size_t XN_ELEMS = (size_t)B_ * T_ * C_;
  size_t off = 0;
  float* stats = (float*)(ws + off); off += 256;
  float2* partials = (float2*)(ws + off); off += 16 * 64 * sizeof(float2);
  short* xn    = (short*)(ws + off); off += XN_ELEMS * 2;
  short* wqkvT = (short*)(ws + off); off += (size_t)1536 * 512 * 2;
  short* woT   = (short*)(ws + off); off += (size_t)512 * 512 * 2;
  short* qkv   = (short*)(ws + off); off += (size_t)B_ * T_ * 1536 * 2;
  short* vTb   = (short*)(ws + off); off += XN_ELEMS * 2;
  short* ao    = (short*)(ws + off); off += XN_ELEMS * 2;

  stats1_kernel<<<dim3(64, 16), 256, 0, stream>>>(x, partials);
  stats2_kernel<<<16, 64, 0, stream>>>(partials, stats);
  norm_kernel<<<8192, 256, 0, stream>>>(x, gamma, beta, stats, xn);
  transpose_w_all<<<4096, 256, 0, stream>>>(wq, wk, wv, wo, wqkvT, woT);

  gemm_qkv<<<dim3(12, 128), 256, 0, stream>>>(xn, wqkvT, bq, bk, bv, qkv);

  vtrans_kernel<<<dim3(8, 8, 16), 256, 0, stream>>>(qkv, vTb);
  attn_kernel<<<dim3(128, 16), 256, 0, stream>>>(qkv, qkv + 512, vTb, ao);

  gemm_out<<<dim3(4, 128), 256, 0, stream>>>(ao, woT, bo, x, out);
}

// Round 2
// 252.693 us; speedup vs baseline: 1.0054x; 1.0054x over previous
//
#include <hip/hip_runtime.h>
#include <hip/hip_bf16.h>

typedef __attribute__((ext_vector_type(8))) short short8;
typedef __attribute__((ext_vector_type(4))) short short4v;
typedef __attribute__((ext_vector_type(4))) float f32x4;

#define B_ 16
#define T_ 1024
#define C_ 512
#define NH 8
#define HD 64

__device__ __forceinline__ short f2bf(float f) {
  union { float f; unsigned u; } v;
  v.f = f;
  unsigned r = v.u + 0x7fffu + ((v.u >> 16) & 1u);
  return (short)(r >> 16);
}

__device__ __forceinline__ short2 pack_bf2(float a, float b) {
  __hip_bfloat162 t = __float22bfloat162_rn(make_float2(a, b));
  short2 r;
  __builtin_memcpy(&r, &t, 4);
  return r;
}

// bare v_exp_f32: computes 2^x. The softmax scale folds log2(e) into Q
// at gemm_qkv, so scores arrive pre-multiplied — saves one v_mul per exp.
__device__ __forceinline__ float fexp2(float x) {
  float r;
  asm("v_exp_f32 %0, %1" : "=v"(r) : "v"(x));
  return r;
}

__device__ __forceinline__ void gload_lds16(const short* g, short* l) {
  __builtin_amdgcn_global_load_lds(
      (const __attribute__((address_space(1))) void*)g,
      (__attribute__((address_space(3))) void*)l, 16, 0, 0);
}

// ---------------- stage 1a: partial sums ----------------
__global__ __launch_bounds__(256) void stats1_kernel(const float* __restrict__ x,
                                                     float2* __restrict__ partials) {
  int chunk = blockIdx.x;
  int b = blockIdx.y;
  int tid = threadIdx.x;
  const float4* xb = (const float4*)(x + (size_t)b * 524288 + (size_t)chunk * 8192);
  float s = 0.f, s2 = 0.f;
#pragma unroll
  for (int i = 0; i < 8; i++) {
    float4 v = xb[tid + i * 256];
    s  += v.x + v.y + v.z + v.w;
    s2 += v.x * v.x + v.y * v.y + v.z * v.z + v.w * v.w;
  }
  __shared__ float ls[256], ls2[256];
  ls[tid] = s; ls2[tid] = s2;
  __syncthreads();
  for (int o = 128; o > 0; o >>= 1) {
    if (tid < o) { ls[tid] += ls[tid + o]; ls2[tid] += ls2[tid + o]; }
    __syncthreads();
  }
  if (tid == 0) partials[b * 64 + chunk] = make_float2(ls[0], ls2[0]);
}

// ---------------- stage 1b: final reduce ----------------
__global__ __launch_bounds__(64) void stats2_kernel(const float2* __restrict__ partials,
                                                    float* __restrict__ stats) {
  int b = blockIdx.x;
  float2 p = partials[b * 64 + threadIdx.x];
  float s = p.x, s2 = p.y;
#pragma unroll
  for (int off = 1; off < 64; off <<= 1) {
    s  += __shfl_xor(s,  off, 64);
    s2 += __shfl_xor(s2, off, 64);
  }
  if (threadIdx.x == 0) {
    float mean = s * (1.f / 524288.f);
    float var  = s2 * (1.f / 524288.f) - mean * mean;
    stats[b * 2]     = mean;
    stats[b * 2 + 1] = rsqrtf(var + 1e-5f);
  }
}

// ---------------- stage 2: normalize + affine -> bf16 ----------------
__global__ __launch_bounds__(256) void norm_kernel(const float* __restrict__ x,
                                                   const float* __restrict__ gamma,
                                                   const float* __restrict__ beta,
                                                   const float* __restrict__ stats,
                                                   short* __restrict__ xn) {
  size_t i4 = (size_t)blockIdx.x * 256 + threadIdx.x;
  float4 v = ((const float4*)x)[i4];
  size_t i = i4 * 4;
  int b = (int)(i >> 19);
  int c = (int)(i & 511);
  float mean = stats[b * 2], rstd = stats[b * 2 + 1];
  short4v o;
  o[0] = f2bf((v.x - mean) * rstd * gamma[c + 0] + beta[c + 0]);
  o[1] = f2bf((v.y - mean) * rstd * gamma[c + 1] + beta[c + 1]);
  o[2] = f2bf((v.z - mean) * rstd * gamma[c + 2] + beta[c + 2]);
  o[3] = f2bf((v.w - mean) * rstd * gamma[c + 3] + beta[c + 3]);
  ((short4v*)xn)[i4] = o;
}

// ---------------- stage 3: weights fp32 (K,N) -> bf16 transposed ----------------
__global__ __launch_bounds__(256) void transpose_w_all(const float* __restrict__ wq,
                                                       const float* __restrict__ wk,
                                                       const float* __restrict__ wv,
                                                       const float* __restrict__ wo,
                                                       short* __restrict__ wqkvT,
                                                       short* __restrict__ woT) {
  int o = blockIdx.x * 256 + threadIdx.x;
  int sel = o >> 18;
  int oo = o & 262143;
  int k = oo >> 9, n = oo & 511;
  const float* w = (sel == 0) ? wq : (sel == 1) ? wk : (sel == 2) ? wv : wo;
  float val = w[oo];
  if (sel < 3) wqkvT[((size_t)(sel * 512 + n)) * 512 + k] = f2bf(val);
  else         woT[(size_t)n * 512 + k] = f2bf(val);
}

// ---------------- stage 4: fused QKV GEMM (m97 structure) ----------------
// Q segment (seg 0) pre-scaled by 0.125*log2(e): folds both the softmax
// 1/sqrt(64) scale AND the exp->exp2 base conversion (softmax is
// base-invariant when applied consistently; attn uses raw v_exp_f32).
__global__ __launch_bounds__(256) void gemm_qkv(const short* __restrict__ A,
                                                const short* __restrict__ Bt,
                                                const float* __restrict__ bq,
                                                const float* __restrict__ bk,
                                                const float* __restrict__ bv,
                                                short* __restrict__ C) {
  __shared__ __align__(16) short As[128 * 32];
  __shared__ __align__(16) short Bs[128 * 32];
  int tid = threadIdx.x;
  int w = tid >> 6, lane = tid & 63;
  int quad = lane >> 4, l16 = lane & 15;
  int mw = (w >> 1) * 64, nw = (w & 1) * 64;
  int seg = (blockIdx.x * 128) >> 9;
  const float* bias = (seg == 0) ? bq : (seg == 1) ? bk : bv;
  float smul = (seg == 0) ? 0.18033688011112042f : 1.0f;
  const short* Atile = A + (size_t)(blockIdx.y * 128) * 512;
  const short* Btile = Bt + (size_t)(blockIdx.x * 128) * 512;
  int srow = (w << 4) + (lane >> 2);
  int scol = (lane & 3) * 8;
  f32x4 acc[4][4] = {};
  for (int k0 = 0; k0 < 512; k0 += 32) {
    __syncthreads();
    gload_lds16(&Atile[(size_t)srow * 512 + k0 + scol],        &As[w * 512]);
    gload_lds16(&Atile[(size_t)(srow + 64) * 512 + k0 + scol], &As[2048 + w * 512]);
    gload_lds16(&Btile[(size_t)srow * 512 + k0 + scol],        &Bs[w * 512]);
    gload_lds16(&Btile[(size_t)(srow + 64) * 512 + k0 + scol], &Bs[2048 + w * 512]);
    __syncthreads();
    short8 af[4], bf[4];
#pragma unroll
    for (int i = 0; i < 4; i++) af[i] = *(const short8*)(&As[(mw + i * 16 + l16) * 32 + quad * 8]);
#pragma unroll
    for (int i = 0; i < 4; i++) bf[i] = *(const short8*)(&Bs[(nw + i * 16 + l16) * 32 + quad * 8]);
#pragma unroll
    for (int mi = 0; mi < 4; mi++)
#pragma unroll
      for (int ni = 0; ni < 4; ni++)
        acc[mi][ni] = __builtin_amdgcn_mfma_f32_16x16x32_bf16(af[mi], bf[ni], acc[mi][ni], 0, 0, 0);
  }
  int m0 = blockIdx.y * 128 + mw;
  int n0 = blockIdx.x * 128 + nw;
#pragma unroll
  for (int mi = 0; mi < 4; mi++)
#pragma unroll
    for (int ni = 0; ni < 4; ni++) {
      int col = n0 + ni * 16 + l16;
      float bval = bias[col & 511];
#pragma unroll
      for (int r = 0; r < 4; r++) {
        int row = m0 + mi * 16 + quad * 4 + r;
        C[(size_t)row * 1536 + col] = f2bf((acc[mi][ni][r] + bval) * smul);
      }
    }
}

// ---------------- stage 6: GEMM + bias + residual (fp32 out) ----------------
__global__ __launch_bounds__(256) void gemm_out(const short* __restrict__ A,
                                                const short* __restrict__ Bt,
                                                const float* __restrict__ bias,
                                                const float* __restrict__ xres,
                                                float* __restrict__ out) {
  __shared__ __align__(16) short As[128 * 32];
  __shared__ __align__(16) short Bs[128 * 32];
  int tid = threadIdx.x;
  int w = tid >> 6, lane = tid & 63;
  int quad = lane >> 4, l16 = lane & 15;
  int mw = (w >> 1) * 64, nw = (w & 1) * 64;
  const short* Atile = A + (size_t)(blockIdx.y * 128) * 512;
  const short* Btile = Bt + (size_t)(blockIdx.x * 128) * 512;
  int srow = (w << 4) + (lane >> 2);
  int scol = (lane & 3) * 8;
  f32x4 acc[4][4] = {};
  for (int k0 = 0; k0 < 512; k0 += 32) {
    __syncthreads();
    gload_lds16(&Atile[(size_t)srow * 512 + k0 + scol],        &As[w * 512]);
    gload_lds16(&Atile[(size_t)(srow + 64) * 512 + k0 + scol], &As[2048 + w * 512]);
    gload_lds16(&Btile[(size_t)srow * 512 + k0 + scol],        &Bs[w * 512]);
    gload_lds16(&Btile[(size_t)(srow + 64) * 512 + k0 + scol], &Bs[2048 + w * 512]);
    __syncthreads();
    short8 af[4], bf[4];
#pragma unroll
    for (int i = 0; i < 4; i++) af[i] = *(const short8*)(&As[(mw + i * 16 + l16) * 32 + quad * 8]);
#pragma unroll
    for (int i = 0; i < 4; i++) bf[i] = *(const short8*)(&Bs[(nw + i * 16 + l16) * 32 + quad * 8]);
#pragma unroll
    for (int mi = 0; mi < 4; mi++)
#pragma unroll
      for (int ni = 0; ni < 4; ni++)
        acc[mi][ni] = __builtin_amdgcn_mfma_f32_16x16x32_bf16(af[mi], bf[ni], acc[mi][ni], 0, 0, 0);
  }
  int m0 = blockIdx.y * 128 + mw;
  int n0 = blockIdx.x * 128 + nw;
#pragma unroll
  for (int mi = 0; mi < 4; mi++)
#pragma unroll
    for (int ni = 0; ni < 4; ni++) {
      int col = n0 + ni * 16 + l16;
      float bval = bias[col];
#pragma unroll
      for (int r = 0; r < 4; r++) {
        int row = m0 + mi * 16 + quad * 4 + r;
        out[(size_t)row * 512 + col] = acc[mi][ni][r] + bval + xres[(size_t)row * 512 + col];
      }
    }
}

// ---------------- stage 4b: V -> vT[b][h][d][slot-permuted keys] ----------------
// Slot layout per 128-key chunk: slot = w*32 + q*8 + half*4 + r for key
// kt = half*64 + w*16 + q*4 + r, so attn's PV A-frag (wave w, quad q) is one
// contiguous 16B read straight from GLOBAL (no LDS staging needed in attn).
__global__ __launch_bounds__(256) void vtrans_kernel(const short* __restrict__ qkv,
                                                     short* __restrict__ vT) {
  int chunk = blockIdx.x;  // 0..7 (128-token chunks)
  int h  = blockIdx.y;
  int b  = blockIdx.z;
  int tid = threadIdx.x;
  __shared__ short TB[128 * 72];
  const short* src = qkv + ((size_t)b * T_ + chunk * 128) * 1536 + 1024 + (size_t)h * 64;
#pragma unroll
  for (int i = 0; i < 4; i++) {
    int idx = tid + i * 256;
    int t = idx >> 3, c = idx & 7;
    *(short8*)(&TB[t * 72 + c * 8]) = *(const short8*)(src + (size_t)t * 1536 + c * 8);
  }
  __syncthreads();
  short* dst = vT + ((size_t)(b * 8 + h) * 64) * 1024 + chunk * 128;
#pragma unroll
  for (int i = 0; i < 4; i++) {
    int idx = tid + i * 256;
    int d = idx >> 4, sc = idx & 15;
    int w2 = sc >> 2, q2 = sc & 3;
    short8 o;
#pragma unroll
    for (int sg = 0; sg < 8; sg++) {
      int half = sg >> 2, r = sg & 3;
      o[sg] = TB[(half * 64 + w2 * 16 + q2 * 4 + r) * 72 + d];
    }
    *(short8*)(dst + (size_t)d * 1024 + sc * 8) = o;
  }
}

// ---------------- stage 5: attention — 2-phase pipelined K-LDS, V direct ----------------
// Lesson r0->r1: pure register pipelining regresses (compiler sinks the
// prefetch loads; VGPR=100 proved the 2-deep K pipeline never materialized;
// latency-bound at VALUBusy 24%). Lesson r(-1): the 2-barrier-per-tile
// staged loop leaves ~34% issue idle (stage latency fully exposed).
// This version: K double-buffered in LDS via global_load_lds (side-effecting
// intrinsic -> compiler cannot sink the issue), stage of tile t+1 issued
// BEFORE compute of tile t, ONE barrier per tile (race-free because the
// buffer being written was last ds_read before the previous barrier).
// V fragments load global->reg directly (vtrans made them contiguous 16B;
// L2-resident) and are issued before the K-stage so the fine-grained vmcnt
// wait for V does not force stage completion. Epilogue unchanged.
__global__ __launch_bounds__(256) void attn_kernel(const short* __restrict__ Q,
                                                   const short* __restrict__ Kmat,
                                                   const short* __restrict__ vTg,
                                                   short* __restrict__ O) {
  int tid = threadIdx.x;
  int w = tid >> 6, lane = tid & 63;
  int quad = lane >> 4, l16 = lane & 15;
  int bh = blockIdx.x;   // b*8+h
  int qt = blockIdx.y;
  int b = bh >> 3, h = bh & 7;
  size_t base  = ((size_t)b * T_) * 1536 + (size_t)h * 64;
  size_t vbase = ((size_t)bh * 64) * 1024;
  size_t obase = ((size_t)b * T_) * 512 + (size_t)h * 64;
  int qrow0 = qt * 64;

  __shared__ __align__(16) char smem[32768 + 1024];
  short* KTb[2];
  KTb[0] = (short*)smem;                    // K dbuf half 0: 128 keys x 64d, swizzled
  KTb[1] = (short*)(smem + 16384);          // K dbuf half 1
  float* Lbuf = (float*)smem;               // epilogue union [q][d] pad 68 (17408B)
  float* denomL = (float*)(smem + 32768);   // outside both K buffers

  // Q as B-frags: B[k=d=quad*8+j][n=q=l16], 4 q-tiles x 2 d-halves
  short8 qf0[4], qf1[4];
#pragma unroll
  for (int g = 0; g < 4; g++) {
    const short* qp = Q + base + (size_t)(qrow0 + g * 16 + l16) * 1536 + quad * 8;
    qf0[g] = *(const short8*)qp;
    qf1[g] = *(const short8*)(qp + 32);
  }

  // K staging descriptors: lane's 16B block index bk = w*256 + n*64 + lane,
  // bank swizzle applied on the GLOBAL address side (LDS dst stays linear).
  const short* ksrc[4];
#pragma unroll
  for (int n = 0; n < 4; n++) {
    int bk = w * 256 + n * 64 + lane;
    int key = bk >> 3, jc = bk & 7;
    int dcol = jc ^ (key & 7);
    ksrc[n] = Kmat + base + (size_t)key * 1536 + dcol * 8;
  }

  // V fragment base: d-row = l16 (+f*16), key-slot = w*4+quad (vtrans layout)
  const short* vp0 = vTg + vbase + (size_t)l16 * 1024 + (w * 4 + quad) * 8;

  // K fragment LDS offsets (shorts), loop-invariant
  int l7 = l16 & 7;
  int kA0 = ((w * 16 + l16) * 8 + (quad ^ l7)) * 8;
  int kA1 = ((w * 16 + l16) * 8 + ((quad + 4) ^ l7)) * 8;
  int kB0 = kA0 + 4096;   // key + 64
  int kB1 = kA1 + 4096;

  f32x4 oacc[4][4] = {};   // O^T[d-tile f][q-tile g]
  float lsum[4] = {0.f, 0.f, 0.f, 0.f};

  // prologue: stage tile 0 into buffer 0
#pragma unroll
  for (int n = 0; n < 4; n++)
    gload_lds16(ksrc[n], KTb[0] + (w * 256 + n * 64) * 8);

#pragma unroll
  for (int t = 0; t < 8; t++) {
    short* KTc = KTb[t & 1];
    short* KTn = KTb[(t + 1) & 1];
    __syncthreads();   // drains vmcnt: K(t) staged; KTn's last readers done
    // V fragments for tile t: global->reg, issued first (vmcnt wait for
    // these lands after QK+exp and doesn't cover the stage ops below)
    short8 vfr[4];
#pragma unroll
    for (int f = 0; f < 4; f++)
      vfr[f] = *(const short8*)(vp0 + (size_t)f * 16384 + t * 128);
    // stage K(t+1) into the other buffer — in flight across this whole phase
    if (t < 7) {
#pragma unroll
      for (int n = 0; n < 4; n++)
        gload_lds16(ksrc[n] + (size_t)(t + 1) * 196608, KTn + (w * 256 + n * 64) * 8);
    }
    // K fragments for tile t from LDS
    short8 ka0 = *(const short8*)(KTc + kA0);
    short8 ka1 = *(const short8*)(KTc + kA1);
    short8 kb0 = *(const short8*)(KTc + kB0);
    short8 kb1 = *(const short8*)(KTc + kB1);

#pragma unroll
    for (int g = 0; g < 4; g++) {
      f32x4 za = {}, zb = {};
      za = __builtin_amdgcn_mfma_f32_16x16x32_bf16(ka0, qf0[g], za, 0, 0, 0);
      za = __builtin_amdgcn_mfma_f32_16x16x32_bf16(ka1, qf1[g], za, 0, 0, 0);
      zb = __builtin_amdgcn_mfma_f32_16x16x32_bf16(kb0, qf0[g], zb, 0, 0, 0);
      zb = __builtin_amdgcn_mfma_f32_16x16x32_bf16(kb1, qf1[g], zb, 0, 0, 0);
      float pa0 = fexp2(za[0]), pa1 = fexp2(za[1]);
      float pa2 = fexp2(za[2]), pa3 = fexp2(za[3]);
      float pb0 = fexp2(zb[0]), pb1 = fexp2(zb[1]);
      float pb2 = fexp2(zb[2]), pb3 = fexp2(zb[3]);
      lsum[g] += (pa0 + pa1) + (pa2 + pa3) + ((pb0 + pb1) + (pb2 + pb3));
      short2 a01 = pack_bf2(pa0, pa1), a23 = pack_bf2(pa2, pa3);
      short2 b01 = pack_bf2(pb0, pb1), b23 = pack_bf2(pb2, pb3);
      short8 pf;
      pf[0] = a01.x; pf[1] = a01.y; pf[2] = a23.x; pf[3] = a23.y;
      pf[4] = b01.x; pf[5] = b01.y; pf[6] = b23.x; pf[7] = b23.y;
#pragma unroll
      for (int f = 0; f < 4; f++)
        oacc[f][g] = __builtin_amdgcn_mfma_f32_16x16x32_bf16(vfr[f], pf, oacc[f][g], 0, 0, 0);
    }
  }

  // per-lane lsum covers this wave's keys for query g*16+l16; sum over quads
#pragma unroll
  for (int g = 0; g < 4; g++) {
    lsum[g] += __shfl_xor(lsum[g], 16, 64);
    lsum[g] += __shfl_xor(lsum[g], 32, 64);
  }
  if (quad == 0) {
#pragma unroll
    for (int g = 0; g < 4; g++) denomL[w * 64 + g * 16 + l16] = lsum[g];
  }
  // sequential cross-wave accumulation of O^T into Lbuf (transposed to [q][d])
  for (int ww = 0; ww < 4; ww++) {
    __syncthreads();
    if (w == ww) {
#pragma unroll
      for (int g = 0; g < 4; g++)
#pragma unroll
        for (int f = 0; f < 4; f++) {
          float* p = &Lbuf[(g * 16 + l16) * 68 + f * 16 + quad * 4];
          if (ww == 0) *(f32x4*)p = oacc[f][g];
          else         *(f32x4*)p = *(f32x4*)p + oacc[f][g];
        }
    }
  }
  __syncthreads();

  // coalesced writeout: thread -> (q = tid/4, 16-wide d segment)
  int q = tid >> 2, seg = tid & 3;
  float dn = denomL[q] + denomL[64 + q] + denomL[128 + q] + denomL[192 + q];
  float rinv = __frcp_rn(dn);
  const float* row = &Lbuf[q * 68 + seg * 16];
  short8 o0, o1;
#pragma unroll
  for (int i = 0; i < 8; i++) o0[i] = f2bf(row[i] * rinv);
#pragma unroll
  for (int i = 0; i < 8; i++) o1[i] = f2bf(row[8 + i] * rinv);
  short* op = O + obase + (size_t)(qrow0 + q) * 512 + seg * 16;
  *(short8*)op = o0;
  *(short8*)(op + 8) = o1;
}

extern "C" void kernel_launch(void* const* d_in, const int* in_sizes, int n_in,
                              void* d_out, int out_size, void* d_ws, size_t ws_size,
                              hipStream_t stream) {
  const float* x     = (const float*)d_in[0];
  const float* gamma = (const float*)d_in[1];
  const float* beta  = (const float*)d_in[2];
  const float* wq    = (const float*)d_in[3];
  const float* bq    = (const float*)d_in[4];
  const float* wk    = (const float*)d_in[5];
  const float* bk    = (const float*)d_in[6];
  const float* wv    = (const float*)d_in[7];
  const float* bv    = (const float*)d_in[8];
  const float* wo    = (const float*)d_in[9];
  const float* bo    = (const float*)d_in[10];
  float* out = (float*)d_out;

  char* ws = (char*)d_ws;
  const size_t XN_ELEMS = (size_t)B_ * T_ * C_;
  size_t off = 0;
  float* stats = (float*)(ws + off); off += 256;
  float2* partials = (float2*)(ws + off); off += 16 * 64 * sizeof(float2);
  short* xn    = (short*)(ws + off); off += XN_ELEMS * 2;
  short* wqkvT = (short*)(ws + off); off += (size_t)1536 * 512 * 2;
  short* woT   = (short*)(ws + off); off += (size_t)512 * 512 * 2;
  short* qkv   = (short*)(ws + off); off += (size_t)B_ * T_ * 1536 * 2;
  short* vTb   = (short*)(ws + off); off += XN_ELEMS * 2;
  short* ao    = (short*)(ws + off); off += XN_ELEMS * 2;

  stats1_kernel<<<dim3(64, 16), 256, 0, stream>>>(x, partials);
  stats2_kernel<<<16, 64, 0, stream>>>(partials, stats);
  norm_kernel<<<8192, 256, 0, stream>>>(x, gamma, beta, stats, xn);
  transpose_w_all<<<4096, 256, 0, stream>>>(wq, wk, wv, wo, wqkvT, woT);

  gemm_qkv<<<dim3(12, 128), 256, 0, stream>>>(xn, wqkvT, bq, bk, bv, qkv);

  vtrans_kernel<<<dim3(8, 8, 16), 256, 0, stream>>>(qkv, vTb);
  attn_kernel<<<dim3(128, 16), 256, 0, stream>>>(qkv, qkv + 512, vTb, ao);

  gemm_out<<<dim3(4, 128), 256, 0, stream>>>(ao, woT, bo, x, out);
}

// Round 3
// 246.663 us; speedup vs baseline: 1.0300x; 1.0244x over previous
//
#include <hip/hip_runtime.h>
#include <hip/hip_bf16.h>

typedef __attribute__((ext_vector_type(8))) short short8;
typedef __attribute__((ext_vector_type(4))) short short4v;
typedef __attribute__((ext_vector_type(4))) float f32x4;

#define B_ 16
#define T_ 1024
#define C_ 512
#define NH 8
#define HD 64

__device__ __forceinline__ short f2bf(float f) {
  union { float f; unsigned u; } v;
  v.f = f;
  unsigned r = v.u + 0x7fffu + ((v.u >> 16) & 1u);
  return (short)(r >> 16);
}

__device__ __forceinline__ short2 pack_bf2(float a, float b) {
  __hip_bfloat162 t = __float22bfloat162_rn(make_float2(a, b));
  short2 r;
  __builtin_memcpy(&r, &t, 4);
  return r;
}

// bare v_exp_f32: computes 2^x. The softmax scale folds log2(e) into Q
// at gemm_qkv, so scores arrive pre-multiplied — saves one v_mul per exp.
__device__ __forceinline__ float fexp2(float x) {
  float r;
  asm("v_exp_f32 %0, %1" : "=v"(r) : "v"(x));
  return r;
}

__device__ __forceinline__ void gload_lds16(const short* g, short* l) {
  __builtin_amdgcn_global_load_lds(
      (const __attribute__((address_space(1))) void*)g,
      (__attribute__((address_space(3))) void*)l, 16, 0, 0);
}

// ---------------- stage 1a: partial sums ----------------
__global__ __launch_bounds__(256) void stats1_kernel(const float* __restrict__ x,
                                                     float2* __restrict__ partials) {
  int chunk = blockIdx.x;
  int b = blockIdx.y;
  int tid = threadIdx.x;
  const float4* xb = (const float4*)(x + (size_t)b * 524288 + (size_t)chunk * 8192);
  float s = 0.f, s2 = 0.f;
#pragma unroll
  for (int i = 0; i < 8; i++) {
    float4 v = xb[tid + i * 256];
    s  += v.x + v.y + v.z + v.w;
    s2 += v.x * v.x + v.y * v.y + v.z * v.z + v.w * v.w;
  }
  __shared__ float ls[256], ls2[256];
  ls[tid] = s; ls2[tid] = s2;
  __syncthreads();
  for (int o = 128; o > 0; o >>= 1) {
    if (tid < o) { ls[tid] += ls[tid + o]; ls2[tid] += ls2[tid + o]; }
    __syncthreads();
  }
  if (tid == 0) partials[b * 64 + chunk] = make_float2(ls[0], ls2[0]);
}

// ---------------- stage 1b: final reduce ----------------
__global__ __launch_bounds__(64) void stats2_kernel(const float2* __restrict__ partials,
                                                    float* __restrict__ stats) {
  int b = blockIdx.x;
  float2 p = partials[b * 64 + threadIdx.x];
  float s = p.x, s2 = p.y;
#pragma unroll
  for (int off = 1; off < 64; off <<= 1) {
    s  += __shfl_xor(s,  off, 64);
    s2 += __shfl_xor(s2, off, 64);
  }
  if (threadIdx.x == 0) {
    float mean = s * (1.f / 524288.f);
    float var  = s2 * (1.f / 524288.f) - mean * mean;
    stats[b * 2]     = mean;
    stats[b * 2 + 1] = rsqrtf(var + 1e-5f);
  }
}

// ---------------- stage 2: normalize + affine -> bf16 ----------------
__global__ __launch_bounds__(256) void norm_kernel(const float* __restrict__ x,
                                                   const float* __restrict__ gamma,
                                                   const float* __restrict__ beta,
                                                   const float* __restrict__ stats,
                                                   short* __restrict__ xn) {
  size_t i4 = (size_t)blockIdx.x * 256 + threadIdx.x;
  float4 v = ((const float4*)x)[i4];
  size_t i = i4 * 4;
  int b = (int)(i >> 19);
  int c = (int)(i & 511);
  float mean = stats[b * 2], rstd = stats[b * 2 + 1];
  short4v o;
  o[0] = f2bf((v.x - mean) * rstd * gamma[c + 0] + beta[c + 0]);
  o[1] = f2bf((v.y - mean) * rstd * gamma[c + 1] + beta[c + 1]);
  o[2] = f2bf((v.z - mean) * rstd * gamma[c + 2] + beta[c + 2]);
  o[3] = f2bf((v.w - mean) * rstd * gamma[c + 3] + beta[c + 3]);
  ((short4v*)xn)[i4] = o;
}

// ---------------- stage 3: weights fp32 (K,N) -> bf16 transposed ----------------
__global__ __launch_bounds__(256) void transpose_w_all(const float* __restrict__ wq,
                                                       const float* __restrict__ wk,
                                                       const float* __restrict__ wv,
                                                       const float* __restrict__ wo,
                                                       short* __restrict__ wqkvT,
                                                       short* __restrict__ woT) {
  int o = blockIdx.x * 256 + threadIdx.x;
  int sel = o >> 18;
  int oo = o & 262143;
  int k = oo >> 9, n = oo & 511;
  const float* w = (sel == 0) ? wq : (sel == 1) ? wk : (sel == 2) ? wv : wo;
  float val = w[oo];
  if (sel < 3) wqkvT[((size_t)(sel * 512 + n)) * 512 + k] = f2bf(val);
  else         woT[(size_t)n * 512 + k] = f2bf(val);
}

// ---------------- stage 4: fused QKV GEMM (m97 structure) ----------------
// Q segment (seg 0) pre-scaled by 0.125*log2(e): folds softmax 1/sqrt(64)
// AND the exp->exp2 base conversion. Q,K write to the compact qkv buffer
// (1024 cols: Q|K). The V segment (seg 2) writes DIRECTLY in the permuted
// vT layout that attn's PV step consumes (slot = mi*32+quad*8+half*4+r is
// closed within each thread's 4-row accumulator -> one packed 8B store),
// eliminating the former vtrans kernel and 32MB of intermediate traffic.
__global__ __launch_bounds__(256) void gemm_qkv(const short* __restrict__ A,
                                                const short* __restrict__ Bt,
                                                const float* __restrict__ bq,
                                                const float* __restrict__ bk,
                                                const float* __restrict__ bv,
                                                short* __restrict__ C,
                                                short* __restrict__ vT) {
  __shared__ __align__(16) short As[128 * 32];
  __shared__ __align__(16) short Bs[128 * 32];
  int tid = threadIdx.x;
  int w = tid >> 6, lane = tid & 63;
  int quad = lane >> 4, l16 = lane & 15;
  int mw = (w >> 1) * 64, nw = (w & 1) * 64;
  int seg = (blockIdx.x * 128) >> 9;
  const float* bias = (seg == 0) ? bq : (seg == 1) ? bk : bv;
  float smul = (seg == 0) ? 0.18033688011112042f : 1.0f;
  const short* Atile = A + (size_t)(blockIdx.y * 128) * 512;
  const short* Btile = Bt + (size_t)(blockIdx.x * 128) * 512;
  int srow = (w << 4) + (lane >> 2);
  int scol = (lane & 3) * 8;
  f32x4 acc[4][4] = {};
  for (int k0 = 0; k0 < 512; k0 += 32) {
    __syncthreads();
    gload_lds16(&Atile[(size_t)srow * 512 + k0 + scol],        &As[w * 512]);
    gload_lds16(&Atile[(size_t)(srow + 64) * 512 + k0 + scol], &As[2048 + w * 512]);
    gload_lds16(&Btile[(size_t)srow * 512 + k0 + scol],        &Bs[w * 512]);
    gload_lds16(&Btile[(size_t)(srow + 64) * 512 + k0 + scol], &Bs[2048 + w * 512]);
    __syncthreads();
    short8 af[4], bf[4];
#pragma unroll
    for (int i = 0; i < 4; i++) af[i] = *(const short8*)(&As[(mw + i * 16 + l16) * 32 + quad * 8]);
#pragma unroll
    for (int i = 0; i < 4; i++) bf[i] = *(const short8*)(&Bs[(nw + i * 16 + l16) * 32 + quad * 8]);
#pragma unroll
    for (int mi = 0; mi < 4; mi++)
#pragma unroll
      for (int ni = 0; ni < 4; ni++)
        acc[mi][ni] = __builtin_amdgcn_mfma_f32_16x16x32_bf16(af[mi], bf[ni], acc[mi][ni], 0, 0, 0);
  }
  int m0 = blockIdx.y * 128 + mw;
  int n0 = blockIdx.x * 128 + nw;
  if (seg < 2) {
#pragma unroll
    for (int mi = 0; mi < 4; mi++)
#pragma unroll
      for (int ni = 0; ni < 4; ni++) {
        int col = n0 + ni * 16 + l16;        // 0..1023 (Q|K)
        float bval = bias[col & 511];
#pragma unroll
        for (int r = 0; r < 4; r++) {
          int row = m0 + mi * 16 + quad * 4 + r;
          C[(size_t)row * 1024 + col] = f2bf((acc[mi][ni][r] + bval) * smul);
        }
      }
  } else {
    // V -> vT[(b*8+h)*64 + d][chunk*128 + slot]; slot = mi*32+quad*8+half*4+r
    int b = blockIdx.y >> 3;
    int chunk = blockIdx.y & 7;
    int half = mw >> 6;                      // 0 or 1
#pragma unroll
    for (int mi = 0; mi < 4; mi++)
#pragma unroll
      for (int ni = 0; ni < 4; ni++) {
        int c = (n0 - 1024) + ni * 16 + l16; // 0..511 v-col
        int h = c >> 6, d = c & 63;
        float bval = bias[c];
        short4v pk;
#pragma unroll
        for (int r = 0; r < 4; r++) pk[r] = f2bf(acc[mi][ni][r] + bval);
        short* dst = vT + ((size_t)((b * 8 + h) * 64 + d)) * 1024
                        + chunk * 128 + mi * 32 + quad * 8 + half * 4;
        *(short4v*)dst = pk;
      }
  }
}

// ---------------- stage 6: GEMM + bias + residual (fp32 out) ----------------
__global__ __launch_bounds__(256) void gemm_out(const short* __restrict__ A,
                                                const short* __restrict__ Bt,
                                                const float* __restrict__ bias,
                                                const float* __restrict__ xres,
                                                float* __restrict__ out) {
  __shared__ __align__(16) short As[128 * 32];
  __shared__ __align__(16) short Bs[128 * 32];
  int tid = threadIdx.x;
  int w = tid >> 6, lane = tid & 63;
  int quad = lane >> 4, l16 = lane & 15;
  int mw = (w >> 1) * 64, nw = (w & 1) * 64;
  const short* Atile = A + (size_t)(blockIdx.y * 128) * 512;
  const short* Btile = Bt + (size_t)(blockIdx.x * 128) * 512;
  int srow = (w << 4) + (lane >> 2);
  int scol = (lane & 3) * 8;
  f32x4 acc[4][4] = {};
  for (int k0 = 0; k0 < 512; k0 += 32) {
    __syncthreads();
    gload_lds16(&Atile[(size_t)srow * 512 + k0 + scol],        &As[w * 512]);
    gload_lds16(&Atile[(size_t)(srow + 64) * 512 + k0 + scol], &As[2048 + w * 512]);
    gload_lds16(&Btile[(size_t)srow * 512 + k0 + scol],        &Bs[w * 512]);
    gload_lds16(&Btile[(size_t)(srow + 64) * 512 + k0 + scol], &Bs[2048 + w * 512]);
    __syncthreads();
    short8 af[4], bf[4];
#pragma unroll
    for (int i = 0; i < 4; i++) af[i] = *(const short8*)(&As[(mw + i * 16 + l16) * 32 + quad * 8]);
#pragma unroll
    for (int i = 0; i < 4; i++) bf[i] = *(const short8*)(&Bs[(nw + i * 16 + l16) * 32 + quad * 8]);
#pragma unroll
    for (int mi = 0; mi < 4; mi++)
#pragma unroll
      for (int ni = 0; ni < 4; ni++)
        acc[mi][ni] = __builtin_amdgcn_mfma_f32_16x16x32_bf16(af[mi], bf[ni], acc[mi][ni], 0, 0, 0);
  }
  int m0 = blockIdx.y * 128 + mw;
  int n0 = blockIdx.x * 128 + nw;
#pragma unroll
  for (int mi = 0; mi < 4; mi++)
#pragma unroll
    for (int ni = 0; ni < 4; ni++) {
      int col = n0 + ni * 16 + l16;
      float bval = bias[col];
#pragma unroll
      for (int r = 0; r < 4; r++) {
        int row = m0 + mi * 16 + quad * 4 + r;
        out[(size_t)row * 512 + col] = acc[mi][ni][r] + bval + xres[(size_t)row * 512 + col];
      }
    }
}

// ---------------- stage 5: attention — 2-phase pipelined K-LDS, V direct ----------------
// r2 lesson: schedule changes (1-barrier dbuf vs 2-barrier) don't move time;
// combined issue util ~49% with ~2.9K cyc wall per ~600-cyc wave-tile means
// memory-latency-stall-bound. Root cause candidate: per-XCD K/V working set
// was 16 bh x 256KB = 4MB == L2 size -> thrash -> HBM-latency stalls
// (FETCH 75MB vs 48MB unique). Fix: XCD-chunked swizzle — XCD x (= lin%8)
// processes bh in [16x,16x+16), its 16 qt-blocks consecutively. Each bh's
// K/V is fetched by exactly ONE xcd, working set ~256KB << 4MB L2.
__global__ __launch_bounds__(256) void attn_kernel(const short* __restrict__ Q,
                                                   const short* __restrict__ Kmat,
                                                   const short* __restrict__ vTg,
                                                   short* __restrict__ O) {
  int tid = threadIdx.x;
  int w = tid >> 6, lane = tid & 63;
  int quad = lane >> 4, l16 = lane & 15;
  int lin = blockIdx.y * 128 + blockIdx.x;   // linear dispatch id (x fastest)
  int bh = (lin & 7) * 16 + (lin >> 7);      // XCD-chunked: xcd owns 16 bh
  int qt = (lin >> 3) & 15;                  // 16 same-bh blocks consecutive
  int b = bh >> 3, h = bh & 7;
  size_t base  = ((size_t)b * T_) * 1024 + (size_t)h * 64;
  size_t vbase = ((size_t)bh * 64) * 1024;
  size_t obase = ((size_t)b * T_) * 512 + (size_t)h * 64;
  int qrow0 = qt * 64;

  __shared__ __align__(16) char smem[32768 + 1024];
  short* KTb[2];
  KTb[0] = (short*)smem;                    // K dbuf half 0: 128 keys x 64d, swizzled
  KTb[1] = (short*)(smem + 16384);          // K dbuf half 1
  float* Lbuf = (float*)smem;               // epilogue union [q][d] pad 68 (17408B)
  float* denomL = (float*)(smem + 32768);   // outside both K buffers

  // Q as B-frags: B[k=d=quad*8+j][n=q=l16], 4 q-tiles x 2 d-halves
  short8 qf0[4], qf1[4];
#pragma unroll
  for (int g = 0; g < 4; g++) {
    const short* qp = Q + base + (size_t)(qrow0 + g * 16 + l16) * 1024 + quad * 8;
    qf0[g] = *(const short8*)qp;
    qf1[g] = *(const short8*)(qp + 32);
  }

  // K staging descriptors: lane's 16B block index bk = w*256 + n*64 + lane,
  // bank swizzle applied on the GLOBAL address side (LDS dst stays linear).
  const short* ksrc[4];
#pragma unroll
  for (int n = 0; n < 4; n++) {
    int bk = w * 256 + n * 64 + lane;
    int key = bk >> 3, jc = bk & 7;
    int dcol = jc ^ (key & 7);
    ksrc[n] = Kmat + base + (size_t)key * 1024 + dcol * 8;
  }

  // V fragment base: d-row = l16 (+f*16), key-slot = w*4+quad (vT layout)
  const short* vp0 = vTg + vbase + (size_t)l16 * 1024 + (w * 4 + quad) * 8;

  // K fragment LDS offsets (shorts), loop-invariant
  int l7 = l16 & 7;
  int kA0 = ((w * 16 + l16) * 8 + (quad ^ l7)) * 8;
  int kA1 = ((w * 16 + l16) * 8 + ((quad + 4) ^ l7)) * 8;
  int kB0 = kA0 + 4096;   // key + 64
  int kB1 = kA1 + 4096;

  f32x4 oacc[4][4] = {};   // O^T[d-tile f][q-tile g]
  float lsum[4] = {0.f, 0.f, 0.f, 0.f};

  // prologue: stage tile 0 into buffer 0
#pragma unroll
  for (int n = 0; n < 4; n++)
    gload_lds16(ksrc[n], KTb[0] + (w * 256 + n * 64) * 8);

#pragma unroll
  for (int t = 0; t < 8; t++) {
    short* KTc = KTb[t & 1];
    short* KTn = KTb[(t + 1) & 1];
    __syncthreads();   // drains vmcnt: K(t) staged; KTn's last readers done
    // V fragments for tile t: global->reg, issued first
    short8 vfr[4];
#pragma unroll
    for (int f = 0; f < 4; f++)
      vfr[f] = *(const short8*)(vp0 + (size_t)f * 16384 + t * 128);
    // stage K(t+1) into the other buffer — in flight across this whole phase
    if (t < 7) {
#pragma unroll
      for (int n = 0; n < 4; n++)
        gload_lds16(ksrc[n] + (size_t)(t + 1) * 131072, KTn + (w * 256 + n * 64) * 8);
    }
    // K fragments for tile t from LDS
    short8 ka0 = *(const short8*)(KTc + kA0);
    short8 ka1 = *(const short8*)(KTc + kA1);
    short8 kb0 = *(const short8*)(KTc + kB0);
    short8 kb1 = *(const short8*)(KTc + kB1);

#pragma unroll
    for (int g = 0; g < 4; g++) {
      f32x4 za = {}, zb = {};
      za = __builtin_amdgcn_mfma_f32_16x16x32_bf16(ka0, qf0[g], za, 0, 0, 0);
      za = __builtin_amdgcn_mfma_f32_16x16x32_bf16(ka1, qf1[g], za, 0, 0, 0);
      zb = __builtin_amdgcn_mfma_f32_16x16x32_bf16(kb0, qf0[g], zb, 0, 0, 0);
      zb = __builtin_amdgcn_mfma_f32_16x16x32_bf16(kb1, qf1[g], zb, 0, 0, 0);
      float pa0 = fexp2(za[0]), pa1 = fexp2(za[1]);
      float pa2 = fexp2(za[2]), pa3 = fexp2(za[3]);
      float pb0 = fexp2(zb[0]), pb1 = fexp2(zb[1]);
      float pb2 = fexp2(zb[2]), pb3 = fexp2(zb[3]);
      lsum[g] += (pa0 + pa1) + (pa2 + pa3) + ((pb0 + pb1) + (pb2 + pb3));
      short2 a01 = pack_bf2(pa0, pa1), a23 = pack_bf2(pa2, pa3);
      short2 b01 = pack_bf2(pb0, pb1), b23 = pack_bf2(pb2, pb3);
      short8 pf;
      pf[0] = a01.x; pf[1] = a01.y; pf[2] = a23.x; pf[3] = a23.y;
      pf[4] = b01.x; pf[5] = b01.y; pf[6] = b23.x; pf[7] = b23.y;
#pragma unroll
      for (int f = 0; f < 4; f++)
        oacc[f][g] = __builtin_amdgcn_mfma_f32_16x16x32_bf16(vfr[f], pf, oacc[f][g], 0, 0, 0);
    }
  }

  // per-lane lsum covers this wave's keys for query g*16+l16; sum over quads
#pragma unroll
  for (int g = 0; g < 4; g++) {
    lsum[g] += __shfl_xor(lsum[g], 16, 64);
    lsum[g] += __shfl_xor(lsum[g], 32, 64);
  }
  if (quad == 0) {
#pragma unroll
    for (int g = 0; g < 4; g++) denomL[w * 64 + g * 16 + l16] = lsum[g];
  }
  // sequential cross-wave accumulation of O^T into Lbuf (transposed to [q][d])
  for (int ww = 0; ww < 4; ww++) {
    __syncthreads();
    if (w == ww) {
#pragma unroll
      for (int g = 0; g < 4; g++)
#pragma unroll
        for (int f = 0; f < 4; f++) {
          float* p = &Lbuf[(g * 16 + l16) * 68 + f * 16 + quad * 4];
          if (ww == 0) *(f32x4*)p = oacc[f][g];
          else         *(f32x4*)p = *(f32x4*)p + oacc[f][g];
        }
    }
  }
  __syncthreads();

  // coalesced writeout: thread -> (q = tid/4, 16-wide d segment)
  int q = tid >> 2, seg = tid & 3;
  float dn = denomL[q] + denomL[64 + q] + denomL[128 + q] + denomL[192 + q];
  float rinv = __frcp_rn(dn);
  const float* row = &Lbuf[q * 68 + seg * 16];
  short8 o0, o1;
#pragma unroll
  for (int i = 0; i < 8; i++) o0[i] = f2bf(row[i] * rinv);
#pragma unroll
  for (int i = 0; i < 8; i++) o1[i] = f2bf(row[8 + i] * rinv);
  short* op = O + obase + (size_t)(qrow0 + q) * 512 + seg * 16;
  *(short8*)op = o0;
  *(short8*)(op + 8) = o1;
}

extern "C" void kernel_launch(void* const* d_in, const int* in_sizes, int n_in,
                              void* d_out, int out_size, void* d_ws, size_t ws_size,
                              hipStream_t stream) {
  const float* x     = (const float*)d_in[0];
  const float* gamma = (const float*)d_in[1];
  const float* beta  = (const float*)d_in[2];
  const float* wq    = (const float*)d_in[3];
  const float* bq    = (const float*)d_in[4];
  const float* wk    = (const float*)d_in[5];
  const float* bk    = (const float*)d_in[6];
  const float* wv    = (const float*)d_in[7];
  const float* bv    = (const float*)d_in[8];
  const float* wo    = (const float*)d_in[9];
  const float* bo    = (const float*)d_in[10];
  float* out = (float*)d_out;

  char* ws = (char*)d_ws;
  const size_t XN_ELEMS = (size_t)B_ * T_ * C_;
  size_t off = 0;
  float* stats = (float*)(ws + off); off += 256;
  float2* partials = (float2*)(ws + off); off += 16 * 64 * sizeof(float2);
  short* xn    = (short*)(ws + off); off += XN_ELEMS * 2;
  short* wqkvT = (short*)(ws + off); off += (size_t)1536 * 512 * 2;
  short* woT   = (short*)(ws + off); off += (size_t)512 * 512 * 2;
  short* qkv   = (short*)(ws + off); off += (size_t)B_ * T_ * 1024 * 2;  // Q|K compact
  short* vTb   = (short*)(ws + off); off += XN_ELEMS * 2;
  short* ao    = (short*)(ws + off); off += XN_ELEMS * 2;

  stats1_kernel<<<dim3(64, 16), 256, 0, stream>>>(x, partials);
  stats2_kernel<<<16, 64, 0, stream>>>(partials, stats);
  norm_kernel<<<8192, 256, 0, stream>>>(x, gamma, beta, stats, xn);
  transpose_w_all<<<4096, 256, 0, stream>>>(wq, wk, wv, wo, wqkvT, woT);

  gemm_qkv<<<dim3(12, 128), 256, 0, stream>>>(xn, wqkvT, bq, bk, bv, qkv, vTb);

  attn_kernel<<<dim3(128, 16), 256, 0, stream>>>(qkv, qkv + 512, vTb, ao);

  gemm_out<<<dim3(4, 128), 256, 0, stream>>>(ao, woT, bo, x, out);
}

// Round 6
// 242.339 us; speedup vs baseline: 1.0483x; 1.0178x over previous
//
#include <hip/hip_runtime.h>
#include <hip/hip_bf16.h>

typedef __attribute__((ext_vector_type(8))) short short8;
typedef __attribute__((ext_vector_type(4))) short short4v;
typedef __attribute__((ext_vector_type(4))) float f32x4;

#define B_ 16
#define T_ 1024
#define C_ 512
#define NH 8
#define HD 64

__device__ __forceinline__ short f2bf(float f) {
  union { float f; unsigned u; } v;
  v.f = f;
  unsigned r = v.u + 0x7fffu + ((v.u >> 16) & 1u);
  return (short)(r >> 16);
}

__device__ __forceinline__ short2 pack_bf2(float a, float b) {
  __hip_bfloat162 t = __float22bfloat162_rn(make_float2(a, b));
  short2 r;
  __builtin_memcpy(&r, &t, 4);
  return r;
}

// bare v_exp_f32: computes 2^x. The softmax scale folds log2(e) into Q
// at gemm_qkv, so scores arrive pre-multiplied — saves one v_mul per exp.
__device__ __forceinline__ float fexp2(float x) {
  float r;
  asm("v_exp_f32 %0, %1" : "=v"(r) : "v"(x));
  return r;
}

__device__ __forceinline__ void gload_lds16(const short* g, short* l) {
  __builtin_amdgcn_global_load_lds(
      (const __attribute__((address_space(1))) void*)g,
      (__attribute__((address_space(3))) void*)l, 16, 0, 0);
}

// ---------------- stage 1: partial sums + weight transpose (merged launch) ----
// Blocks 0..1023: GroupNorm partial sums (chunk = blk&63, b = blk>>6).
// Blocks 1024..5119: fp32 -> bf16 transposed weight prep (former kernel).
// Branch is block-uniform, so the barrier inside the stats path stays legal.
__global__ __launch_bounds__(256) void stats1_trans_kernel(
    const float* __restrict__ x, float2* __restrict__ partials,
    const float* __restrict__ wq, const float* __restrict__ wk,
    const float* __restrict__ wv, const float* __restrict__ wo,
    short* __restrict__ wqkvT, short* __restrict__ woT) {
  int blk = blockIdx.x;
  int tid = threadIdx.x;
  if (blk < 1024) {
    int chunk = blk & 63;
    int b = blk >> 6;
    const float4* xb = (const float4*)(x + (size_t)b * 524288 + (size_t)chunk * 8192);
    float s = 0.f, s2 = 0.f;
#pragma unroll
    for (int i = 0; i < 8; i++) {
      float4 v = xb[tid + i * 256];
      s  += v.x + v.y + v.z + v.w;
      s2 += v.x * v.x + v.y * v.y + v.z * v.z + v.w * v.w;
    }
    __shared__ float ls[256], ls2[256];
    ls[tid] = s; ls2[tid] = s2;
    __syncthreads();
    for (int o = 128; o > 0; o >>= 1) {
      if (tid < o) { ls[tid] += ls[tid + o]; ls2[tid] += ls2[tid + o]; }
      __syncthreads();
    }
    if (tid == 0) partials[b * 64 + chunk] = make_float2(ls[0], ls2[0]);
  } else {
    int o = (blk - 1024) * 256 + tid;
    int sel = o >> 18;
    int oo = o & 262143;
    int k = oo >> 9, n = oo & 511;
    const float* w = (sel == 0) ? wq : (sel == 1) ? wk : (sel == 2) ? wv : wo;
    float val = w[oo];
    if (sel < 3) wqkvT[((size_t)(sel * 512 + n)) * 512 + k] = f2bf(val);
    else         woT[(size_t)n * 512 + k] = f2bf(val);
  }
}

// ---------------- stage 2: normalize + affine -> bf16 (stats2 fused) --------
// Each block covers 1024 contiguous floats of one sample (b = blk>>9) and
// redundantly reduces that sample's 64 partials (512B, L2-hit) in wave 0 —
// removes the former stats2 dispatch + launch gap.
__global__ __launch_bounds__(256) void norm_kernel(const float* __restrict__ x,
                                                   const float* __restrict__ gamma,
                                                   const float* __restrict__ beta,
                                                   const float2* __restrict__ partials,
                                                   short* __restrict__ xn) {
  __shared__ float sm[2];
  int tid = threadIdx.x;
  int b = blockIdx.x >> 9;
  if (tid < 64) {
    float2 p = partials[b * 64 + tid];
    float s = p.x, s2 = p.y;
#pragma unroll
    for (int off = 1; off < 64; off <<= 1) {
      s  += __shfl_xor(s,  off, 64);
      s2 += __shfl_xor(s2, off, 64);
    }
    if (tid == 0) {
      float mean = s * (1.f / 524288.f);
      float var  = s2 * (1.f / 524288.f) - mean * mean;
      sm[0] = mean;
      sm[1] = rsqrtf(var + 1e-5f);
    }
  }
  __syncthreads();
  float mean = sm[0], rstd = sm[1];
  size_t i4 = (size_t)blockIdx.x * 256 + tid;
  float4 v = ((const float4*)x)[i4];
  int c = (int)((i4 * 4) & 511);
  short4v o;
  o[0] = f2bf((v.x - mean) * rstd * gamma[c + 0] + beta[c + 0]);
  o[1] = f2bf((v.y - mean) * rstd * gamma[c + 1] + beta[c + 1]);
  o[2] = f2bf((v.z - mean) * rstd * gamma[c + 2] + beta[c + 2]);
  o[3] = f2bf((v.w - mean) * rstd * gamma[c + 3] + beta[c + 3]);
  ((short4v*)xn)[i4] = o;
}

// ---------------- stage 4: fused QKV GEMM (m97 structure) ----------------
// Q segment (seg 0) pre-scaled by 0.125*log2(e): folds softmax 1/sqrt(64)
// AND the exp->exp2 base conversion. Q,K write to the compact qkv buffer
// (1024 cols: Q|K). The V segment (seg 2) writes DIRECTLY in the permuted
// vT layout that attn's PV step consumes (slot = mi*32+quad*8+half*4+r is
// closed within each thread's 4-row accumulator -> one packed 8B store).
__global__ __launch_bounds__(256) void gemm_qkv(const short* __restrict__ A,
                                                const short* __restrict__ Bt,
                                                const float* __restrict__ bq,
                                                const float* __restrict__ bk,
                                                const float* __restrict__ bv,
                                                short* __restrict__ C,
                                                short* __restrict__ vT) {
  __shared__ __align__(16) short As[128 * 32];
  __shared__ __align__(16) short Bs[128 * 32];
  int tid = threadIdx.x;
  int w = tid >> 6, lane = tid & 63;
  int quad = lane >> 4, l16 = lane & 15;
  int mw = (w >> 1) * 64, nw = (w & 1) * 64;
  int seg = (blockIdx.x * 128) >> 9;
  const float* bias = (seg == 0) ? bq : (seg == 1) ? bk : bv;
  float smul = (seg == 0) ? 0.18033688011112042f : 1.0f;
  const short* Atile = A + (size_t)(blockIdx.y * 128) * 512;
  const short* Btile = Bt + (size_t)(blockIdx.x * 128) * 512;
  int srow = (w << 4) + (lane >> 2);
  int scol = (lane & 3) * 8;
  f32x4 acc[4][4] = {};
  for (int k0 = 0; k0 < 512; k0 += 32) {
    __syncthreads();
    gload_lds16(&Atile[(size_t)srow * 512 + k0 + scol],        &As[w * 512]);
    gload_lds16(&Atile[(size_t)(srow + 64) * 512 + k0 + scol], &As[2048 + w * 512]);
    gload_lds16(&Btile[(size_t)srow * 512 + k0 + scol],        &Bs[w * 512]);
    gload_lds16(&Btile[(size_t)(srow + 64) * 512 + k0 + scol], &Bs[2048 + w * 512]);
    __syncthreads();
    short8 af[4], bf[4];
#pragma unroll
    for (int i = 0; i < 4; i++) af[i] = *(const short8*)(&As[(mw + i * 16 + l16) * 32 + quad * 8]);
#pragma unroll
    for (int i = 0; i < 4; i++) bf[i] = *(const short8*)(&Bs[(nw + i * 16 + l16) * 32 + quad * 8]);
#pragma unroll
    for (int mi = 0; mi < 4; mi++)
#pragma unroll
      for (int ni = 0; ni < 4; ni++)
        acc[mi][ni] = __builtin_amdgcn_mfma_f32_16x16x32_bf16(af[mi], bf[ni], acc[mi][ni], 0, 0, 0);
  }
  int m0 = blockIdx.y * 128 + mw;
  int n0 = blockIdx.x * 128 + nw;
  if (seg < 2) {
#pragma unroll
    for (int mi = 0; mi < 4; mi++)
#pragma unroll
      for (int ni = 0; ni < 4; ni++) {
        int col = n0 + ni * 16 + l16;        // 0..1023 (Q|K)
        float bval = bias[col & 511];
#pragma unroll
        for (int r = 0; r < 4; r++) {
          int row = m0 + mi * 16 + quad * 4 + r;
          C[(size_t)row * 1024 + col] = f2bf((acc[mi][ni][r] + bval) * smul);
        }
      }
  } else {
    // V -> vT[(b*8+h)*64 + d][chunk*128 + slot]; slot = mi*32+quad*8+half*4+r
    int b = blockIdx.y >> 3;
    int chunk = blockIdx.y & 7;
    int half = mw >> 6;                      // 0 or 1
#pragma unroll
    for (int mi = 0; mi < 4; mi++)
#pragma unroll
      for (int ni = 0; ni < 4; ni++) {
        int c = (n0 - 1024) + ni * 16 + l16; // 0..511 v-col
        int h = c >> 6, d = c & 63;
        float bval = bias[c];
        short4v pk;
#pragma unroll
        for (int r = 0; r < 4; r++) pk[r] = f2bf(acc[mi][ni][r] + bval);
        short* dst = vT + ((size_t)((b * 8 + h) * 64 + d)) * 1024
                        + chunk * 128 + mi * 32 + quad * 8 + half * 4;
        *(short4v*)dst = pk;
      }
  }
}

// ---------------- stage 6: GEMM + bias + residual (fp32 out) ----------------
__global__ __launch_bounds__(256) void gemm_out(const short* __restrict__ A,
                                                const short* __restrict__ Bt,
                                                const float* __restrict__ bias,
                                                const float* __restrict__ xres,
                                                float* __restrict__ out) {
  __shared__ __align__(16) short As[128 * 32];
  __shared__ __align__(16) short Bs[128 * 32];
  int tid = threadIdx.x;
  int w = tid >> 6, lane = tid & 63;
  int quad = lane >> 4, l16 = lane & 15;
  int mw = (w >> 1) * 64, nw = (w & 1) * 64;
  const short* Atile = A + (size_t)(blockIdx.y * 128) * 512;
  const short* Btile = Bt + (size_t)(blockIdx.x * 128) * 512;
  int srow = (w << 4) + (lane >> 2);
  int scol = (lane & 3) * 8;
  f32x4 acc[4][4] = {};
  for (int k0 = 0; k0 < 512; k0 += 32) {
    __syncthreads();
    gload_lds16(&Atile[(size_t)srow * 512 + k0 + scol],        &As[w * 512]);
    gload_lds16(&Atile[(size_t)(srow + 64) * 512 + k0 + scol], &As[2048 + w * 512]);
    gload_lds16(&Btile[(size_t)srow * 512 + k0 + scol],        &Bs[w * 512]);
    gload_lds16(&Btile[(size_t)(srow + 64) * 512 + k0 + scol], &Bs[2048 + w * 512]);
    __syncthreads();
    short8 af[4], bf[4];
#pragma unroll
    for (int i = 0; i < 4; i++) af[i] = *(const short8*)(&As[(mw + i * 16 + l16) * 32 + quad * 8]);
#pragma unroll
    for (int i = 0; i < 4; i++) bf[i] = *(const short8*)(&Bs[(nw + i * 16 + l16) * 32 + quad * 8]);
#pragma unroll
    for (int mi = 0; mi < 4; mi++)
#pragma unroll
      for (int ni = 0; ni < 4; ni++)
        acc[mi][ni] = __builtin_amdgcn_mfma_f32_16x16x32_bf16(af[mi], bf[ni], acc[mi][ni], 0, 0, 0);
  }
  int m0 = blockIdx.y * 128 + mw;
  int n0 = blockIdx.x * 128 + nw;
#pragma unroll
  for (int mi = 0; mi < 4; mi++)
#pragma unroll
    for (int ni = 0; ni < 4; ni++) {
      int col = n0 + ni * 16 + l16;
      float bval = bias[col];
#pragma unroll
      for (int r = 0; r < 4; r++) {
        int row = m0 + mi * 16 + quad * 4 + r;
        out[(size_t)row * 512 + col] = acc[mi][ni][r] + bval + xres[(size_t)row * 512 + col];
      }
    }
}

// ---------------- stage 5: attention — r3-proven structure + T5 setprio -----
// REVERTED to the r3 kernel verbatim (r4's 8-wave merge produced NaN; cause
// not identified by inspection -> it will be retried as a sole-change round).
// Only addition: s_setprio(1) around the QK and PV MFMA clusters (pure
// scheduler hint, zero correctness risk; catalog T5 shows +4-7% on attn
// with multiple independent blocks resident per CU).
__global__ __launch_bounds__(256) void attn_kernel(const short* __restrict__ Q,
                                                   const short* __restrict__ Kmat,
                                                   const short* __restrict__ vTg,
                                                   short* __restrict__ O) {
  int tid = threadIdx.x;
  int w = tid >> 6, lane = tid & 63;
  int quad = lane >> 4, l16 = lane & 15;
  int lin = blockIdx.y * 128 + blockIdx.x;   // linear dispatch id (x fastest)
  int bh = (lin & 7) * 16 + (lin >> 7);      // XCD-chunked: xcd owns 16 bh
  int qt = (lin >> 3) & 15;                  // 16 same-bh blocks consecutive
  int b = bh >> 3, h = bh & 7;
  size_t base  = ((size_t)b * T_) * 1024 + (size_t)h * 64;
  size_t vbase = ((size_t)bh * 64) * 1024;
  size_t obase = ((size_t)b * T_) * 512 + (size_t)h * 64;
  int qrow0 = qt * 64;

  __shared__ __align__(16) char smem[32768 + 1024];
  short* KTb[2];
  KTb[0] = (short*)smem;                    // K dbuf half 0: 128 keys x 64d, swizzled
  KTb[1] = (short*)(smem + 16384);          // K dbuf half 1
  float* Lbuf = (float*)smem;               // epilogue union [q][d] pad 68 (17408B)
  float* denomL = (float*)(smem + 32768);   // outside both K buffers

  // Q as B-frags: B[k=d=quad*8+j][n=q=l16], 4 q-tiles x 2 d-halves
  short8 qf0[4], qf1[4];
#pragma unroll
  for (int g = 0; g < 4; g++) {
    const short* qp = Q + base + (size_t)(qrow0 + g * 16 + l16) * 1024 + quad * 8;
    qf0[g] = *(const short8*)qp;
    qf1[g] = *(const short8*)(qp + 32);
  }

  // K staging descriptors: lane's 16B block index bk = w*256 + n*64 + lane,
  // bank swizzle applied on the GLOBAL address side (LDS dst stays linear).
  const short* ksrc[4];
#pragma unroll
  for (int n = 0; n < 4; n++) {
    int bk = w * 256 + n * 64 + lane;
    int key = bk >> 3, jc = bk & 7;
    int dcol = jc ^ (key & 7);
    ksrc[n] = Kmat + base + (size_t)key * 1024 + dcol * 8;
  }

  // V fragment base: d-row = l16 (+f*16), key-slot = w*4+quad (vT layout)
  const short* vp0 = vTg + vbase + (size_t)l16 * 1024 + (w * 4 + quad) * 8;

  // K fragment LDS offsets (shorts), loop-invariant
  int l7 = l16 & 7;
  int kA0 = ((w * 16 + l16) * 8 + (quad ^ l7)) * 8;
  int kA1 = ((w * 16 + l16) * 8 + ((quad + 4) ^ l7)) * 8;
  int kB0 = kA0 + 4096;   // key + 64
  int kB1 = kA1 + 4096;

  f32x4 oacc[4][4] = {};   // O^T[d-tile f][q-tile g]
  float lsum[4] = {0.f, 0.f, 0.f, 0.f};

  // prologue: stage tile 0 into buffer 0
#pragma unroll
  for (int n = 0; n < 4; n++)
    gload_lds16(ksrc[n], KTb[0] + (w * 256 + n * 64) * 8);

#pragma unroll
  for (int t = 0; t < 8; t++) {
    short* KTc = KTb[t & 1];
    short* KTn = KTb[(t + 1) & 1];
    __syncthreads();   // drains vmcnt: K(t) staged; KTn's last readers done
    // V fragments for tile t: global->reg, issued first
    short8 vfr[4];
#pragma unroll
    for (int f = 0; f < 4; f++)
      vfr[f] = *(const short8*)(vp0 + (size_t)f * 16384 + t * 128);
    // stage K(t+1) into the other buffer — in flight across this whole phase
    if (t < 7) {
#pragma unroll
      for (int n = 0; n < 4; n++)
        gload_lds16(ksrc[n] + (size_t)(t + 1) * 131072, KTn + (w * 256 + n * 64) * 8);
    }
    // K fragments for tile t from LDS
    short8 ka0 = *(const short8*)(KTc + kA0);
    short8 ka1 = *(const short8*)(KTc + kA1);
    short8 kb0 = *(const short8*)(KTc + kB0);
    short8 kb1 = *(const short8*)(KTc + kB1);

#pragma unroll
    for (int g = 0; g < 4; g++) {
      f32x4 za = {}, zb = {};
      __builtin_amdgcn_s_setprio(1);
      za = __builtin_amdgcn_mfma_f32_16x16x32_bf16(ka0, qf0[g], za, 0, 0, 0);
      za = __builtin_amdgcn_mfma_f32_16x16x32_bf16(ka1, qf1[g], za, 0, 0, 0);
      zb = __builtin_amdgcn_mfma_f32_16x16x32_bf16(kb0, qf0[g], zb, 0, 0, 0);
      zb = __builtin_amdgcn_mfma_f32_16x16x32_bf16(kb1, qf1[g], zb, 0, 0, 0);
      __builtin_amdgcn_s_setprio(0);
      float pa0 = fexp2(za[0]), pa1 = fexp2(za[1]);
      float pa2 = fexp2(za[2]), pa3 = fexp2(za[3]);
      float pb0 = fexp2(zb[0]), pb1 = fexp2(zb[1]);
      float pb2 = fexp2(zb[2]), pb3 = fexp2(zb[3]);
      lsum[g] += (pa0 + pa1) + (pa2 + pa3) + ((pb0 + pb1) + (pb2 + pb3));
      short2 a01 = pack_bf2(pa0, pa1), a23 = pack_bf2(pa2, pa3);
      short2 b01 = pack_bf2(pb0, pb1), b23 = pack_bf2(pb2, pb3);
      short8 pf;
      pf[0] = a01.x; pf[1] = a01.y; pf[2] = a23.x; pf[3] = a23.y;
      pf[4] = b01.x; pf[5] = b01.y; pf[6] = b23.x; pf[7] = b23.y;
      __builtin_amdgcn_s_setprio(1);
#pragma unroll
      for (int f = 0; f < 4; f++)
        oacc[f][g] = __builtin_amdgcn_mfma_f32_16x16x32_bf16(vfr[f], pf, oacc[f][g], 0, 0, 0);
      __builtin_amdgcn_s_setprio(0);
    }
  }

  // per-lane lsum covers this wave's keys for query g*16+l16; sum over quads
#pragma unroll
  for (int g = 0; g < 4; g++) {
    lsum[g] += __shfl_xor(lsum[g], 16, 64);
    lsum[g] += __shfl_xor(lsum[g], 32, 64);
  }
  if (quad == 0) {
#pragma unroll
    for (int g = 0; g < 4; g++) denomL[w * 64 + g * 16 + l16] = lsum[g];
  }
  // sequential cross-wave accumulation of O^T into Lbuf (transposed to [q][d])
  for (int ww = 0; ww < 4; ww++) {
    __syncthreads();
    if (w == ww) {
#pragma unroll
      for (int g = 0; g < 4; g++)
#pragma unroll
        for (int f = 0; f < 4; f++) {
          float* p = &Lbuf[(g * 16 + l16) * 68 + f * 16 + quad * 4];
          if (ww == 0) *(f32x4*)p = oacc[f][g];
          else         *(f32x4*)p = *(f32x4*)p + oacc[f][g];
        }
    }
  }
  __syncthreads();

  // coalesced writeout: thread -> (q = tid/4, 16-wide d segment)
  int q = tid >> 2, seg = tid & 3;
  float dn = denomL[q] + denomL[64 + q] + denomL[128 + q] + denomL[192 + q];
  float rinv = __frcp_rn(dn);
  const float* row = &Lbuf[q * 68 + seg * 16];
  short8 o0, o1;
#pragma unroll
  for (int i = 0; i < 8; i++) o0[i] = f2bf(row[i] * rinv);
#pragma unroll
  for (int i = 0; i < 8; i++) o1[i] = f2bf(row[8 + i] * rinv);
  short* op = O + obase + (size_t)(qrow0 + q) * 512 + seg * 16;
  *(short8*)op = o0;
  *(short8*)(op + 8) = o1;
}

extern "C" void kernel_launch(void* const* d_in, const int* in_sizes, int n_in,
                              void* d_out, int out_size, void* d_ws, size_t ws_size,
                              hipStream_t stream) {
  const float* x     = (const float*)d_in[0];
  const float* gamma = (const float*)d_in[1];
  const float* beta  = (const float*)d_in[2];
  const float* wq    = (const float*)d_in[3];
  const float* bq    = (const float*)d_in[4];
  const float* wk    = (const float*)d_in[5];
  const float* bk    = (const float*)d_in[6];
  const float* wv    = (const float*)d_in[7];
  const float* bv    = (const float*)d_in[8];
  const float* wo    = (const float*)d_in[9];
  const float* bo    = (const float*)d_in[10];
  float* out = (float*)d_out;

  char* ws = (char*)d_ws;
  const size_t XN_ELEMS = (size_t)B_ * T_ * C_;
  size_t off = 0;
  off += 256;                                              // (reserved)
  float2* partials = (float2*)(ws + off); off += 16 * 64 * sizeof(float2);
  short* xn    = (short*)(ws + off); off += XN_ELEMS * 2;
  short* wqkvT = (short*)(ws + off); off += (size_t)1536 * 512 * 2;
  short* woT   = (short*)(ws + off); off += (size_t)512 * 512 * 2;
  short* qkv   = (short*)(ws + off); off += (size_t)B_ * T_ * 1024 * 2;  // Q|K compact
  short* vTb   = (short*)(ws + off); off += XN_ELEMS * 2;
  short* ao    = (short*)(ws + off); off += XN_ELEMS * 2;

  stats1_trans_kernel<<<5120, 256, 0, stream>>>(x, partials, wq, wk, wv, wo, wqkvT, woT);
  norm_kernel<<<8192, 256, 0, stream>>>(x, gamma, beta, partials, xn);

  gemm_qkv<<<dim3(12, 128), 256, 0, stream>>>(xn, wqkvT, bq, bk, bv, qkv, vTb);

  attn_kernel<<<dim3(128, 16), 256, 0, stream>>>(qkv, qkv + 512, vTb, ao);

  gemm_out<<<dim3(4, 128), 256, 0, stream>>>(ao, woT, bo, x, out);
}